// Round 1
// baseline (450.604 us; speedup 1.0000x reference)
//
#include <hip/hip_runtime.h>
#include <stdint.h>

// ---------------------------------------------------------------------------
// LSH layer: out[n,s] = sum_d x[n,d] * W[ids[s],d] + bias[ids[s]]
// Strategy: gather+convert W rows to bf16 in ws, convert x to bf16, then
// m97-style bf16 MFMA GEMM (C = A * B^T) with fused bias epilogue (fp32 out).
// Tolerance is 2% of ref absmax -> bf16 inputs + fp32 accumulation is safe.
// ---------------------------------------------------------------------------

typedef __bf16 bf16x8 __attribute__((ext_vector_type(8)));
typedef float f32x4 __attribute__((ext_vector_type(4)));

#define BM 128
#define BN 128
#define BK 64

__device__ __forceinline__ ushort f2bf(float f) {
  // round-to-nearest-even fp32 -> bf16
  union { float f; uint32_t u; } c; c.f = f;
  uint32_t u = c.u;
  return (ushort)((u + 0x7FFFu + ((u >> 16) & 1u)) >> 16);
}

__global__ void convert_x_kernel(const float* __restrict__ x,
                                 ushort* __restrict__ xb) {
  int i = blockIdx.x * blockDim.x + threadIdx.x;
  float4 v = ((const float4*)x)[i];
  ushort4 o;
  o.x = f2bf(v.x); o.y = f2bf(v.y); o.z = f2bf(v.z); o.w = f2bf(v.w);
  ((ushort4*)xb)[i] = o;
}

// one block per selected neuron: gather row of W (fp32) -> bf16, gather bias
__global__ void gather_kernel(const float* __restrict__ W,
                              const float* __restrict__ bias,
                              const int* __restrict__ ids,
                              ushort* __restrict__ Wg,
                              float* __restrict__ biasg,
                              int D) {
  int s = blockIdx.x;
  int id = ids[s];
  const float4* src = (const float4*)(W + (size_t)id * D);
  ushort4* dst = (ushort4*)(Wg + (size_t)s * D);
  int t = threadIdx.x;  // 256 threads * 4 floats = 1024 = D
  float4 v = src[t];
  ushort4 o;
  o.x = f2bf(v.x); o.y = f2bf(v.y); o.z = f2bf(v.z); o.w = f2bf(v.w);
  dst[t] = o;
  if (t == 0) biasg[s] = bias[id];
}

__device__ __forceinline__ void load_lds16(const void* g, void* l) {
  __builtin_amdgcn_global_load_lds(
      (const __attribute__((address_space(1))) void*)g,
      (__attribute__((address_space(3))) void*)l, 16, 0, 0);
}

// C[M,S] = A[M,K](bf16) * B[S,K](bf16)^T + biasg[S], fp32 out.
// Block 256 threads = 4 waves (2x2 of 64x64), each wave 4x4 of 16x16x32 MFMA.
__global__ __launch_bounds__(256) void gemm_bt_bias(
    const ushort* __restrict__ A, const ushort* __restrict__ B,
    const float* __restrict__ biasg, float* __restrict__ C,
    int M, int S, int K) {
  __shared__ __align__(16) ushort As[BM * BK];
  __shared__ __align__(16) ushort Bs[BN * BK];

  const int tid  = threadIdx.x;
  const int lane = tid & 63;
  const int wave = tid >> 6;
  const int bn = blockIdx.x;   // S / BN tiles (fastest -> shares A tile in L2)
  const int bm = blockIdx.y;   // M / BM tiles

  const int wm = (wave >> 1) * 64;
  const int wn = (wave & 1) * 64;
  const int quad = lane >> 4;
  const int l16  = lane & 15;

  // staging: thread tid loads 16B: row = tid/8 (+i*32), kchunk = (tid%8)*8
  const int srow = tid >> 3;
  const int scol = (tid & 7) * 8;
  const ushort* Ag = A + (size_t)(bm * BM + srow) * K + scol;
  const ushort* Bg = B + (size_t)(bn * BN + srow) * K + scol;
  // LDS dest must be wave-uniform base + lane*16B: As + tid*8 elems == that
  ushort* Asl = As + tid * 8;
  ushort* Bsl = Bs + tid * 8;

  f32x4 acc[4][4] = {};

  for (int kt = 0; kt < K; kt += BK) {
#pragma unroll
    for (int i = 0; i < 4; ++i) {
      load_lds16(Ag + (size_t)(i * 32) * K, Asl + i * 32 * BK);
      load_lds16(Bg + (size_t)(i * 32) * K, Bsl + i * 32 * BK);
    }
    Ag += BK; Bg += BK;
    __syncthreads();  // drains vmcnt(0): LDS writes visible

#pragma unroll
    for (int ks = 0; ks < BK; ks += 32) {
      bf16x8 af[4], bq[4];
#pragma unroll
      for (int i = 0; i < 4; ++i)
        af[i] = *(const bf16x8*)(As + (wm + i * 16 + l16) * BK + ks + quad * 8);
#pragma unroll
      for (int j = 0; j < 4; ++j)
        bq[j] = *(const bf16x8*)(Bs + (wn + j * 16 + l16) * BK + ks + quad * 8);
#pragma unroll
      for (int i = 0; i < 4; ++i)
#pragma unroll
        for (int j = 0; j < 4; ++j)
          acc[i][j] = __builtin_amdgcn_mfma_f32_16x16x32_bf16(
              af[i], bq[j], acc[i][j], 0, 0, 0);
    }
    __syncthreads();  // protect LDS from next stage
  }

  // epilogue: C/D layout col = lane&15, row = quad*4 + reg  [m89/m91 verified]
  const int row0 = bm * BM + wm + quad * 4;
  const int col0 = bn * BN + wn + l16;
#pragma unroll
  for (int j = 0; j < 4; ++j) {
    const int col = col0 + j * 16;
    const float bv = biasg[col];
#pragma unroll
    for (int i = 0; i < 4; ++i) {
#pragma unroll
      for (int r = 0; r < 4; ++r) {
        C[(size_t)(row0 + i * 16 + r) * S + col] = acc[i][j][r] + bv;
      }
    }
  }
}

extern "C" void kernel_launch(void* const* d_in, const int* in_sizes, int n_in,
                              void* d_out, int out_size, void* d_ws, size_t ws_size,
                              hipStream_t stream) {
  const float* x    = (const float*)d_in[0];  // [N, D]
  const float* W    = (const float*)d_in[1];  // [OUT, D]
  const float* bias = (const float*)d_in[2];  // [OUT]
  const int*   ids  = (const int*)d_in[3];    // [S]
  float* out = (float*)d_out;                 // [N, S]

  const int OUTN = in_sizes[2];
  const int S    = in_sizes[3];
  const int D    = in_sizes[1] / OUTN;  // 1024
  const int N    = in_sizes[0] / D;     // 2048

  // workspace layout: Wg bf16 [S,D] | xb bf16 [N,D] | biasg f32 [S]
  ushort* Wg = (ushort*)d_ws;
  ushort* xb = (ushort*)((char*)d_ws + (size_t)S * D * sizeof(ushort));
  float* biasg = (float*)((char*)d_ws + (size_t)S * D * sizeof(ushort)
                          + (size_t)N * D * sizeof(ushort));

  convert_x_kernel<<<(N * D / 4 + 255) / 256, 256, 0, stream>>>(x, xb);
  gather_kernel<<<S, D / 4, 0, stream>>>(W, bias, ids, Wg, biasg, D);

  dim3 grid(S / BN, N / BM);
  gemm_bt_bias<<<grid, 256, 0, stream>>>(xb, Wg, biasg, out, N, S, D);
}

// Round 2
// 433.225 us; speedup vs baseline: 1.0401x; 1.0401x over previous
//
#include <hip/hip_runtime.h>
#include <stdint.h>

// ---------------------------------------------------------------------------
// LSH layer: out[n,s] = sum_d x[n,d] * W[ids[s],d] + bias[ids[s]]
// R2: (1) XOR chunk-swizzled LDS layout in the GEMM -- kills the 16-way
//     bank-group aliasing of the m97-style row-major tile (row stride 128 B
//     == 32 banks) while staying compatible with global_load_lds's forced
//     lane*16B placement (we permute the per-lane GLOBAL address instead).
// (2) gather + x-convert fused into one kernel, 8 rows per gather block.
// ---------------------------------------------------------------------------

typedef __bf16 bf16x8 __attribute__((ext_vector_type(8)));
typedef float f32x4 __attribute__((ext_vector_type(4)));

#define BM 128
#define BN 128
#define BK 64

__device__ __forceinline__ ushort f2bf(float f) {
  union { float f; uint32_t u; } c; c.f = f;
  uint32_t u = c.u;
  return (ushort)((u + 0x7FFFu + ((u >> 16) & 1u)) >> 16);
}

// blocks [0, S/8): gather 8 W rows -> bf16 + bias gather
// blocks [S/8, S/8 + N*D/1024): convert x -> bf16
__global__ __launch_bounds__(256) void prep_kernel(
    const float* __restrict__ x, const float* __restrict__ W,
    const float* __restrict__ bias, const int* __restrict__ ids,
    ushort* __restrict__ Wg, ushort* __restrict__ xb,
    float* __restrict__ biasg, int D, int S) {
  const int t = threadIdx.x;
  const int gblocks = S >> 3;
  if ((int)blockIdx.x < gblocks) {
    const int s0 = blockIdx.x << 3;
    if (t < 8) biasg[s0 + t] = bias[ids[s0 + t]];
#pragma unroll
    for (int r = 0; r < 8; ++r) {
      const int s = s0 + r;
      const int id = ids[s];
      float4 v = ((const float4*)(W + (size_t)id * D))[t];
      ushort4 o;
      o.x = f2bf(v.x); o.y = f2bf(v.y); o.z = f2bf(v.z); o.w = f2bf(v.w);
      ((ushort4*)(Wg + (size_t)s * D))[t] = o;
    }
  } else {
    const int i = (blockIdx.x - gblocks) * 256 + t;
    float4 v = ((const float4*)x)[i];
    ushort4 o;
    o.x = f2bf(v.x); o.y = f2bf(v.y); o.z = f2bf(v.z); o.w = f2bf(v.w);
    ((ushort4*)xb)[i] = o;
  }
}

__device__ __forceinline__ void load_lds16(const void* g, void* l) {
  __builtin_amdgcn_global_load_lds(
      (const __attribute__((address_space(1))) void*)g,
      (__attribute__((address_space(3))) void*)l, 16, 0, 0);
}

// Swizzled LDS addressing: physical chunk p at row r holds logical chunk
// c = p ^ (r & 7). One chunk = 8 ushorts = 16 B. Row = BK = 8 chunks.
__device__ __forceinline__ const ushort* frag_ptr(const ushort* base, int row,
                                                  int c) {
  return base + row * BK + (((c ^ (row & 7)) << 3));
}

// C[M,S] = A[M,K](bf16) * B[S,K](bf16)^T + biasg[S], fp32 out.
// 256 thr = 4 waves (2x2 of 64x64), each wave 4x4 of 16x16x32 MFMA tiles.
__global__ __launch_bounds__(256) void gemm_bt_bias(
    const ushort* __restrict__ A, const ushort* __restrict__ B,
    const float* __restrict__ biasg, float* __restrict__ C,
    int M, int S, int K) {
  __shared__ __align__(16) ushort As[BM * BK];
  __shared__ __align__(16) ushort Bs[BN * BK];

  const int tid  = threadIdx.x;
  const int lane = tid & 63;
  const int wave = tid >> 6;
  const int bn = blockIdx.x;
  const int bm = blockIdx.y;

  const int wm = (wave >> 1) * 64;
  const int wn = (wave & 1) * 64;
  const int quad = lane >> 4;
  const int l16  = lane & 15;

  // staging: thread tid -> LDS slot tid*16B == (row=tid/8, phys chunk=tid%8).
  // phys chunk p holds logical chunk p ^ (row&7)  ->  global col = that chunk.
  const int srow = tid >> 3;
  const int scol = (((tid & 7) ^ (srow & 7)) << 3);
  const ushort* Ag = A + (size_t)(bm * BM + srow) * K + scol;
  const ushort* Bg = B + (size_t)(bn * BN + srow) * K + scol;
  ushort* Asl = As + tid * 8;   // wave-uniform base + lane*16B
  ushort* Bsl = Bs + tid * 8;

  f32x4 acc[4][4] = {};

  for (int kt = 0; kt < K; kt += BK) {
#pragma unroll
    for (int i = 0; i < 4; ++i) {
      load_lds16(Ag + (size_t)(i * 32) * K, Asl + i * 32 * BK);
      load_lds16(Bg + (size_t)(i * 32) * K, Bsl + i * 32 * BK);
    }
    Ag += BK; Bg += BK;
    __syncthreads();

#pragma unroll
    for (int ks = 0; ks < BK; ks += 32) {
      const int c0 = (ks >> 3) + quad;  // logical chunk index for this frag
      bf16x8 af[4], bq[4];
#pragma unroll
      for (int i = 0; i < 4; ++i)
        af[i] = *(const bf16x8*)frag_ptr(As, wm + i * 16 + l16, c0);
#pragma unroll
      for (int j = 0; j < 4; ++j)
        bq[j] = *(const bf16x8*)frag_ptr(Bs, wn + j * 16 + l16, c0);
#pragma unroll
      for (int i = 0; i < 4; ++i)
#pragma unroll
        for (int j = 0; j < 4; ++j)
          acc[i][j] = __builtin_amdgcn_mfma_f32_16x16x32_bf16(
              af[i], bq[j], acc[i][j], 0, 0, 0);
    }
    __syncthreads();
  }

  // epilogue: C/D layout col = lane&15, row = quad*4 + reg  [m89/m91]
  const int row0 = bm * BM + wm + quad * 4;
  const int col0 = bn * BN + wn + l16;
#pragma unroll
  for (int j = 0; j < 4; ++j) {
    const int col = col0 + j * 16;
    const float bv = biasg[col];
#pragma unroll
    for (int i = 0; i < 4; ++i) {
#pragma unroll
      for (int r = 0; r < 4; ++r) {
        C[(size_t)(row0 + i * 16 + r) * S + col] = acc[i][j][r] + bv;
      }
    }
  }
}

extern "C" void kernel_launch(void* const* d_in, const int* in_sizes, int n_in,
                              void* d_out, int out_size, void* d_ws, size_t ws_size,
                              hipStream_t stream) {
  const float* x    = (const float*)d_in[0];  // [N, D]
  const float* W    = (const float*)d_in[1];  // [OUT, D]
  const float* bias = (const float*)d_in[2];  // [OUT]
  const int*   ids  = (const int*)d_in[3];    // [S]
  float* out = (float*)d_out;                 // [N, S]

  const int OUTN = in_sizes[2];
  const int S    = in_sizes[3];
  const int D    = in_sizes[1] / OUTN;  // 1024
  const int N    = in_sizes[0] / D;     // 2048

  // workspace: Wg bf16 [S,D] | xb bf16 [N,D] | biasg f32 [S]
  ushort* Wg = (ushort*)d_ws;
  ushort* xb = (ushort*)((char*)d_ws + (size_t)S * D * sizeof(ushort));
  float* biasg = (float*)((char*)d_ws + (size_t)S * D * sizeof(ushort)
                          + (size_t)N * D * sizeof(ushort));

  const int gather_blocks = S / 8;
  const int conv_blocks = (N * D) / 1024;  // 256 thr * 4 floats
  prep_kernel<<<gather_blocks + conv_blocks, 256, 0, stream>>>(
      x, W, bias, ids, Wg, xb, biasg, D, S);

  dim3 grid(S / BN, N / BM);
  gemm_bt_bias<<<grid, 256, 0, stream>>>(xb, Wg, biasg, out, N, S, D);
}